// Round 11
// baseline (399.033 us; speedup 1.0000x reference)
//
#include <hip/hip_runtime.h>
#include <hip/hip_bf16.h>
#include <math.h>

typedef __attribute__((ext_vector_type(8))) short bf16x8;   // 8 bf16 in 4 VGPRs
typedef __attribute__((ext_vector_type(4))) float f32x4;
typedef unsigned int uint32;
typedef __attribute__((ext_vector_type(2))) unsigned int uint32x2;

#define DMODEL 1024
#define SEQ    2048
#define NB     2
#define NH     16
#define HD     64
#define FDIM   4096
#define NTOK   (NB*SEQ)   // 4096

// ---------------- async global->LDS (wave-uniform LDS base + lane*16) ----------------
__device__ __forceinline__ void async16(const void* g, void* s) {
    __builtin_amdgcn_global_load_lds((const __attribute__((address_space(1))) unsigned int*)g,
                                     (__attribute__((address_space(3))) unsigned int*)s,
                                     16, 0, 0);
}

// ---------------- XCD-aware bijective block swizzle (T1, m204 form) ----------------
// Hardware dispatches linear block ids round-robin across the 8 XCDs; remap so each XCD
// processes a CONTIGUOUS run of row-major tiles -> same-A-panel blocks share one L2.
__device__ __forceinline__ int xcd_swizzle_lin(int lin, int nwg) {
    if (nwg & 7) return lin;          // bijective only when nwg % 8 == 0
    int q = nwg >> 3;
    return (lin & 7) * q + (lin >> 3);
}

// ---------------- merged 4x (1024x1024) transpose: z picks {wq,wk,wv,wo} ----------------
__global__ __launch_bounds__(256) void transpose_cvt4_k(const float* __restrict__ s0,
                                                        const float* __restrict__ s1,
                                                        const float* __restrict__ s2,
                                                        const float* __restrict__ s3,
                                                        __hip_bfloat16* __restrict__ d012,
                                                        __hip_bfloat16* __restrict__ d3) {
    __shared__ __hip_bfloat16 tile[32][33];
    const int z = blockIdx.z;
    const float* src = (z == 0) ? s0 : (z == 1) ? s1 : (z == 2) ? s2 : s3;
    __hip_bfloat16* dst = (z < 3) ? d012 + (size_t)z * DMODEL * DMODEL : d3;
    int tx = threadIdx.x, ty = threadIdx.y;
    int bx = blockIdx.x * 32, by = blockIdx.y * 32;
    for (int i = 0; i < 32; i += 8)
        tile[ty + i][tx] = __float2bfloat16(src[(size_t)(by + ty + i) * DMODEL + bx + tx]);
    __syncthreads();
    for (int i = 0; i < 32; i += 8)
        dst[(size_t)(bx + ty + i) * DMODEL + by + tx] = tile[tx][ty + i];
}

// ---------------- merged w1/w2 transpose: z=0: w1[1024][4096]->w1T[4096][1024];
// z=1: w2[4096][1024]->w2T[1024][4096]. Grid (128,32,2); z=1 swaps tile-index roles. ----
__global__ __launch_bounds__(256) void transpose_cvt2_k(const float* __restrict__ s0,
                                                        const float* __restrict__ s1,
                                                        __hip_bfloat16* __restrict__ d0,
                                                        __hip_bfloat16* __restrict__ d1) {
    __shared__ __hip_bfloat16 tile[32][33];
    const int z = blockIdx.z;
    const float* src = z ? s1 : s0;
    __hip_bfloat16* dst = z ? d1 : d0;
    const int R = z ? FDIM : DMODEL;     // src rows
    const int C = z ? DMODEL : FDIM;     // src cols
    const int bxi = z ? blockIdx.y : blockIdx.x;   // tile index over C
    const int byi = z ? blockIdx.x : blockIdx.y;   // tile index over R
    int tx = threadIdx.x, ty = threadIdx.y;
    int bx = bxi * 32, by = byi * 32;
    for (int i = 0; i < 32; i += 8)
        tile[ty + i][tx] = __float2bfloat16(src[(size_t)(by + ty + i) * C + bx + tx]);
    __syncthreads();
    for (int i = 0; i < 32; i += 8)
        dst[(size_t)(bx + ty + i) * R + by + tx] = tile[tx][ty + i];
}

// ---------------- layernorm: f32 row of 1024, unbiased std (ddof=1), /(std+eps) -> bf16 ----------------
__global__ __launch_bounds__(256) void ln_kernel(const float* __restrict__ x,
                                                 const float* __restrict__ alpha,
                                                 const float* __restrict__ beta,
                                                 __hip_bfloat16* __restrict__ out) {
    const int row = blockIdx.x, tid = threadIdx.x;
    const size_t base = (size_t)row * DMODEL;
    float v[4];
    for (int e = 0; e < 4; ++e) v[e] = x[base + tid * 4 + e];
    float s1 = v[0] + v[1] + v[2] + v[3];
    float s2 = v[0]*v[0] + v[1]*v[1] + v[2]*v[2] + v[3]*v[3];
    for (int off = 32; off > 0; off >>= 1) {
        s1 += __shfl_down(s1, off);
        s2 += __shfl_down(s2, off);
    }
    __shared__ float red[8];
    int w = tid >> 6, lane = tid & 63;
    if (lane == 0) { red[w * 2] = s1; red[w * 2 + 1] = s2; }
    __syncthreads();
    if (tid == 0) {
        float a = 0.f, b = 0.f;
        for (int i = 0; i < 4; ++i) { a += red[2 * i]; b += red[2 * i + 1]; }
        red[0] = a; red[1] = b;
    }
    __syncthreads();
    s1 = red[0]; s2 = red[1];
    float mean = s1 * (1.0f / DMODEL);
    float var  = fmaxf((s2 - (float)DMODEL * mean * mean) * (1.0f / (DMODEL - 1)), 0.f);
    float inv  = 1.0f / (sqrtf(var) + 1e-6f);
    for (int e = 0; e < 4; ++e) {
        int c = tid * 4 + e;
        float y = alpha[c] * (v[e] - mean) * inv + beta[c];
        out[base + c] = __float2bfloat16(y);
    }
}

// ---------------- GEMM (double-buffered, T2-swizzled, T1 XCD-swizzled): C = A @ Bt^T + bias ----------------
// EPI: 0 = bias -> bf16 ; 1 = bias+relu -> bf16 ; 2 = bias + f32 residual -> f32
template <int EPI>
__global__ __launch_bounds__(256) void gemm_bt(const __hip_bfloat16* __restrict__ A,
                                               const __hip_bfloat16* __restrict__ Bt,
                                               const float* __restrict__ bias,
                                               const float* __restrict__ res,
                                               void* __restrict__ Cout,
                                               int M, int N, int K) {
    __shared__ alignas(16) __hip_bfloat16 As[2][128 * 32];
    __shared__ alignas(16) __hip_bfloat16 Bs[2][128 * 32];
    const int tid = threadIdx.x, l = tid & 63;
    const int w = tid >> 6;
    const int wm = w >> 1, wn = w & 1, quad = l >> 4, lc = l & 15;
    const int lin = xcd_swizzle_lin(blockIdx.y * gridDim.x + blockIdx.x, gridDim.x * gridDim.y);
    const int row0 = (lin / gridDim.x) * 128, col0 = (lin % gridDim.x) * 128;
    const int lr = l >> 2, cb = l & 3;
    const int srow = 32 * w + lr;
    const int scol = (cb ^ ((lr >> 1) & 3)) * 8;     // pre-swizzled global source chunk
    const int rsw  = (lc >> 1) & 3;                  // read-side un-swizzle

    f32x4 acc[4][4];
    for (int i = 0; i < 4; ++i)
        for (int j = 0; j < 4; ++j) acc[i][j] = (f32x4){0.f, 0.f, 0.f, 0.f};

    // prologue: stage tile 0 into buffer 0
    for (int c = 0; c < 2; ++c) {
        async16(A  + (size_t)(row0 + srow + 16 * c) * K + scol, (char*)&As[0][0] + w * 2048 + c * 1024);
        async16(Bt + (size_t)(col0 + srow + 16 * c) * K + scol, (char*)&Bs[0][0] + w * 2048 + c * 1024);
    }
    const int NKT = K / 32;
    for (int kt = 0; kt < NKT; ++kt) {
        const int cur = kt & 1;
        __syncthreads();   // drains stage(kt); also fences prev-iter LDS reads
        if (kt + 1 < NKT) {
            const int k1 = (kt + 1) * 32;
            for (int c = 0; c < 2; ++c) {
                async16(A  + (size_t)(row0 + srow + 16 * c) * K + k1 + scol, (char*)&As[cur ^ 1][0] + w * 2048 + c * 1024);
                async16(Bt + (size_t)(col0 + srow + 16 * c) * K + k1 + scol, (char*)&Bs[cur ^ 1][0] + w * 2048 + c * 1024);
            }
        }
        bf16x8 af[4], bfr[4];
        for (int i = 0; i < 4; ++i) af[i]  = *(const bf16x8*)&As[cur][(64 * wm + 16 * i + lc) * 32 + (quad ^ rsw) * 8];
        for (int j = 0; j < 4; ++j) bfr[j] = *(const bf16x8*)&Bs[cur][(64 * wn + 16 * j + lc) * 32 + (quad ^ rsw) * 8];
        for (int i = 0; i < 4; ++i)
            for (int j = 0; j < 4; ++j)
                acc[i][j] = __builtin_amdgcn_mfma_f32_16x16x32_bf16(af[i], bfr[j], acc[i][j], 0, 0, 0);
    }

    __hip_bfloat16* Cb = (__hip_bfloat16*)Cout;
    float* Cf = (float*)Cout;
    for (int j = 0; j < 4; ++j) {
        int col = col0 + 64 * wn + 16 * j + lc;
        float bv = bias[col];
        for (int i = 0; i < 4; ++i) {
            int rbase = row0 + 64 * wm + 16 * i + quad * 4;
            for (int r = 0; r < 4; ++r) {
                size_t idx = (size_t)(rbase + r) * N + col;
                float vacc = acc[i][j][r] + bv;
                if (EPI == 0)      Cb[idx] = __float2bfloat16(vacc);
                else if (EPI == 1) Cb[idx] = __float2bfloat16(fmaxf(vacc, 0.f));
                else               Cf[idx] = vacc + res[idx];
            }
        }
    }
}

// ---------------- in-block split-K GEMM for small-N shapes (N=1024 -> 256 blocks = 1/CU) ----------------
template <int EPI>
__global__ __launch_bounds__(512) void gemm_bt_sk(const __hip_bfloat16* __restrict__ A,
                                                  const __hip_bfloat16* __restrict__ Bt,
                                                  const float* __restrict__ bias,
                                                  const float* __restrict__ res,
                                                  void* __restrict__ Cout,
                                                  int M, int N, int K) {
    __shared__ alignas(16) char smem[65536];   // [As: 2g x 2buf x 8KB][Bs: same]
    const int tid = threadIdx.x, l = tid & 63;
    const int w = tid >> 6;           // 0..7
    const int g = w >> 2;             // K-group
    const int wl = w & 3;             // wave within group
    const int wm = wl >> 1, wn = wl & 1, quad = l >> 4, lc = l & 15;
    const int row0 = blockIdx.y * 128, col0 = blockIdx.x * 128;
    const int lr = l >> 2, cb = l & 3;
    const int srow = 32 * wl + lr;
    const int scol = (cb ^ ((lr >> 1) & 3)) * 8;
    const int rsw  = (lc >> 1) & 3;
    const int Kh = K >> 1;
    const int kbase = g * Kh;

    char* AsBase = smem + (size_t)g * 16384;
    char* BsBase = smem + 32768 + (size_t)g * 16384;

    f32x4 acc[4][4];
    for (int i = 0; i < 4; ++i)
        for (int j = 0; j < 4; ++j) acc[i][j] = (f32x4){0.f, 0.f, 0.f, 0.f};

    // prologue: stage tile 0 into buffer 0 (per group)
    for (int c = 0; c < 2; ++c) {
        async16(A  + (size_t)(row0 + srow + 16 * c) * K + kbase + scol, AsBase + wl * 2048 + c * 1024);
        async16(Bt + (size_t)(col0 + srow + 16 * c) * K + kbase + scol, BsBase + wl * 2048 + c * 1024);
    }
    const int NKT = Kh / 32;
    for (int kt = 0; kt < NKT; ++kt) {
        const int cur = kt & 1;
        __syncthreads();
        if (kt + 1 < NKT) {
            const int k1 = kbase + (kt + 1) * 32;
            for (int c = 0; c < 2; ++c) {
                async16(A  + (size_t)(row0 + srow + 16 * c) * K + k1 + scol, AsBase + (cur ^ 1) * 8192 + wl * 2048 + c * 1024);
                async16(Bt + (size_t)(col0 + srow + 16 * c) * K + k1 + scol, BsBase + (cur ^ 1) * 8192 + wl * 2048 + c * 1024);
            }
        }
        const __hip_bfloat16* Asc = (const __hip_bfloat16*)(AsBase + cur * 8192);
        const __hip_bfloat16* Bsc = (const __hip_bfloat16*)(BsBase + cur * 8192);
        bf16x8 af[4], bfr[4];
        for (int i = 0; i < 4; ++i) af[i]  = *(const bf16x8*)&Asc[(64 * wm + 16 * i + lc) * 32 + (quad ^ rsw) * 8];
        for (int j = 0; j < 4; ++j) bfr[j] = *(const bf16x8*)&Bsc[(64 * wn + 16 * j + lc) * 32 + (quad ^ rsw) * 8];
        for (int i = 0; i < 4; ++i)
            for (int j = 0; j < 4; ++j)
                acc[i][j] = __builtin_amdgcn_mfma_f32_16x16x32_bf16(af[i], bfr[j], acc[i][j], 0, 0, 0);
    }

    // combine: repurpose the whole 64 KB as a 128x128 f32 tile
    __syncthreads();                       // all LDS reads + staged loads drained
    float* comb = (float*)smem;
    if (g == 1) {
        for (int j = 0; j < 4; ++j) {
            int col = 64 * wn + 16 * j + lc;
            int ccol = col ^ ((quad & 1) << 4);          // 2-way-max bank spread
            for (int i = 0; i < 4; ++i) {
                int rb = 64 * wm + 16 * i + quad * 4;
                for (int r = 0; r < 4; ++r)
                    comb[(rb + r) * 128 + ccol] = acc[i][j][r];
            }
        }
    }
    __syncthreads();
    if (g == 0) {
        __hip_bfloat16* Cb = (__hip_bfloat16*)Cout;
        float* Cf = (float*)Cout;
        for (int j = 0; j < 4; ++j) {
            int coll = 64 * wn + 16 * j + lc;
            int ccol = coll ^ ((quad & 1) << 4);
            int col  = col0 + coll;
            float bv = bias[col];
            for (int i = 0; i < 4; ++i) {
                int rbl = 64 * wm + 16 * i + quad * 4;
                for (int r = 0; r < 4; ++r) {
                    size_t idx = (size_t)(row0 + rbl + r) * N + col;
                    float vacc = acc[i][j][r] + comb[(rbl + r) * 128 + ccol] + bv;
                    if (EPI == 0)      Cb[idx] = __float2bfloat16(vacc);
                    else if (EPI == 1) Cb[idx] = __float2bfloat16(fmaxf(vacc, 0.f));
                    else               Cf[idx] = vacc + res[idx];
                }
            }
        }
    }
}

// ---------------- fused QKV GEMM (double-buffered, T2 + T1 swizzled): N = 3072 = [q | k | v] ----------------
__global__ __launch_bounds__(256) void gemm_qkv(const __hip_bfloat16* __restrict__ A,
                                                const __hip_bfloat16* __restrict__ Bt,
                                                const float* __restrict__ bq,
                                                const float* __restrict__ bk,
                                                const float* __restrict__ bv,
                                                __hip_bfloat16* __restrict__ qout,
                                                __hip_bfloat16* __restrict__ kout,
                                                __hip_bfloat16* __restrict__ vTout) {
    const int K = DMODEL;
    __shared__ alignas(16) __hip_bfloat16 As[2][128 * 32];
    __shared__ alignas(16) __hip_bfloat16 Bs[2][128 * 32];
    const int tid = threadIdx.x, l = tid & 63;
    const int w = tid >> 6;
    const int wm = w >> 1, wn = w & 1, quad = l >> 4, lc = l & 15;
    const int lin = xcd_swizzle_lin(blockIdx.y * gridDim.x + blockIdx.x, gridDim.x * gridDim.y);
    const int row0 = (lin / gridDim.x) * 128, col0 = (lin % gridDim.x) * 128;
    const int lr = l >> 2, cb = l & 3;
    const int srow = 32 * w + lr;
    const int scol = (cb ^ ((lr >> 1) & 3)) * 8;
    const int rsw  = (lc >> 1) & 3;

    f32x4 acc[4][4];
    for (int i = 0; i < 4; ++i)
        for (int j = 0; j < 4; ++j) acc[i][j] = (f32x4){0.f, 0.f, 0.f, 0.f};

    for (int c = 0; c < 2; ++c) {
        async16(A  + (size_t)(row0 + srow + 16 * c) * K + scol, (char*)&As[0][0] + w * 2048 + c * 1024);
        async16(Bt + (size_t)(col0 + srow + 16 * c) * K + scol, (char*)&Bs[0][0] + w * 2048 + c * 1024);
    }
    const int NKT = K / 32;
    for (int kt = 0; kt < NKT; ++kt) {
        const int cur = kt & 1;
        __syncthreads();
        if (kt + 1 < NKT) {
            const int k1 = (kt + 1) * 32;
            for (int c = 0; c < 2; ++c) {
                async16(A  + (size_t)(row0 + srow + 16 * c) * K + k1 + scol, (char*)&As[cur ^ 1][0] + w * 2048 + c * 1024);
                async16(Bt + (size_t)(col0 + srow + 16 * c) * K + k1 + scol, (char*)&Bs[cur ^ 1][0] + w * 2048 + c * 1024);
            }
        }
        bf16x8 af[4], bfr[4];
        for (int i = 0; i < 4; ++i) af[i]  = *(const bf16x8*)&As[cur][(64 * wm + 16 * i + lc) * 32 + (quad ^ rsw) * 8];
        for (int j = 0; j < 4; ++j) bfr[j] = *(const bf16x8*)&Bs[cur][(64 * wn + 16 * j + lc) * 32 + (quad ^ rsw) * 8];
        for (int i = 0; i < 4; ++i)
            for (int j = 0; j < 4; ++j)
                acc[i][j] = __builtin_amdgcn_mfma_f32_16x16x32_bf16(af[i], bfr[j], acc[i][j], 0, 0, 0);
    }

    const int seg = col0 >> 10;                       // block-uniform: 0=q, 1=k, 2=v
    const float* bias = (seg == 0) ? bq : (seg == 1) ? bk : bv;
    for (int j = 0; j < 4; ++j) {
        int col  = col0 + 64 * wn + 16 * j + lc;
        int colm = col & (DMODEL - 1);
        float bvx = bias[colm];
        for (int i = 0; i < 4; ++i) {
            int rbase = row0 + 64 * wm + 16 * i + quad * 4;
            for (int r = 0; r < 4; ++r) {
                int trow = rbase + r;
                float vacc = acc[i][j][r] + bvx;
                if (seg == 2) {
                    // V^T: token t=(b,s), colm=(h,d) -> [(b*NH+h)*HD+d][s]
                    int bb = trow >> 11, s = trow & (SEQ - 1);
                    int hh = colm >> 6, d = colm & (HD - 1);
                    vTout[((size_t)(bb * NH + hh) * HD + d) * SEQ + s] = __float2bfloat16(vacc);
                } else {
                    __hip_bfloat16* dst = (seg == 0) ? qout : kout;
                    dst[(size_t)trow * DMODEL + colm] = __float2bfloat16(vacc);
                }
            }
        }
    }
}

// ---------------- flash attention v14 (FINAL, unchanged): QBLK=128 + in-block KV-split ----------------
// Measured-best (78.6us). Variant sweep complete: QBLK=64 100us, QBLK=256 103us (VGPR cliff),
// exp2f 90us (libm), head-major 90us, no-LDS 138us (TA-bound scattered gathers).
__global__ __launch_bounds__(512) void attn_kernel(const __hip_bfloat16* __restrict__ q,
                                                   const __hip_bfloat16* __restrict__ k,
                                                   const __hip_bfloat16* __restrict__ vT,
                                                   const int* __restrict__ mask,
                                                   __hip_bfloat16* __restrict__ ctx) {
    const int qt = blockIdx.x, bh = blockIdx.y;
    const int b = bh >> 4;
    const int q0 = qt * 128;
    const int tid = threadIdx.x, w = tid >> 6, l = tid & 63, quad = l >> 4, lc = l & 15;
    const int g = w >> 2, wl = w & 3;

    __shared__ alignas(16) char smem[65536];
    __hip_bfloat16* KhB = (__hip_bfloat16*)(smem + (size_t)g * 32768);
    __hip_bfloat16* VhB = (__hip_bfloat16*)(smem + (size_t)g * 32768 + 16384);

    const size_t base   = (size_t)b * SEQ * DMODEL + (size_t)(bh & 15) * HD;
    const size_t vtbase = (size_t)bh * HD * SEQ;
    const int gk = g * (SEQ / 2);     // group key base

    bf16x8 qf[2][2];
    for (int s = 0; s < 2; ++s) {
        const __hip_bfloat16* qrow = &q[base + (size_t)(q0 + s * 64 + wl * 16 + lc) * DMODEL];
        qf[s][0] = *(const bf16x8*)&qrow[quad * 8];
        qf[s][1] = *(const bf16x8*)&qrow[32 + quad * 8];
    }

    f32x4 o[2][4];
    for (int s = 0; s < 2; ++s)
        for (int dj = 0; dj < 4; ++dj) o[s][dj] = (f32x4){0.f, 0.f, 0.f, 0.f};
    float rsp2[2] = {0.f, 0.f};

    const int lr  = l >> 2, cb = l & 3;
    const int cbsw = ((cb ^ ((lr >> 1) & 3))) * 8;   // pre-swizzled global source block (stage side)
    const int rsw  = (lc >> 1) & 3;                  // read-side XOR

    // prologue: stage tile 0 into buffer 0 (global source pre-swizzled; LDS dest linear)
    for (int c = 0; c < 2; ++c) {
        const int W = wl * 2 + c;
        const int rr = (W & 3) * 16 + lr, cc8 = (W >> 2) * 32 + cbsw;
        async16(&k [base   + (size_t)(gk + rr) * DMODEL + cc8], (char*)KhB + W * 1024);
        async16(&vT[vtbase + (size_t)rr * SEQ + gk + cc8],      (char*)VhB + W * 1024);
    }

    const int NT = SEQ / 128;   // 16 tiles of 64 keys per group
    for (int kt = 0; kt < NT; ++kt) {
        const int k0 = gk + kt * 64;
        const int cur = kt & 1;

        __syncthreads();   // drains stage(kt); fences prev-iter fragment reads
        if (kt + 1 < NT) {
            const int k1 = k0 + 64;
            for (int c = 0; c < 2; ++c) {
                const int W = wl * 2 + c;
                const int rr = (W & 3) * 16 + lr, cc8 = (W >> 2) * 32 + cbsw;
                async16(&k [base   + (size_t)(k1 + rr) * DMODEL + cc8], (char*)KhB + (cur ^ 1) * 8192 + W * 1024);
                async16(&vT[vtbase + (size_t)rr * SEQ + k1 + cc8],      (char*)VhB + (cur ^ 1) * 8192 + W * 1024);
            }
        }
        // mask -> additive bias (0 / -inf), once per tile (16B-aligned int4 loads)
        float mb[4][4];
        for (int jn = 0; jn < 4; ++jn) {
            int4 mi = *(const int4*)&mask[b * SEQ + k0 + jn * 16 + quad * 4];
            mb[jn][0] = mi.x ? 0.f : -INFINITY;
            mb[jn][1] = mi.y ? 0.f : -INFINITY;
            mb[jn][2] = mi.z ? 0.f : -INFINITY;
            mb[jn][3] = mi.w ? 0.f : -INFINITY;
        }

        bf16x8 kf0[4], kf1[4];
        for (int jn = 0; jn < 4; ++jn) {
            kf0[jn] = *(const bf16x8*)&KhB[(cur * 2 + 0) * 2048 + (jn * 16 + lc) * 32 + (quad ^ rsw) * 8];
            kf1[jn] = *(const bf16x8*)&KhB[(cur * 2 + 1) * 2048 + (jn * 16 + lc) * 32 + (quad ^ rsw) * 8];
        }
        bf16x8 vf0[4], vf1[4];
        for (int dj = 0; dj < 4; ++dj) {
            vf0[dj] = *(const bf16x8*)&VhB[(cur * 2 + 0) * 2048 + (dj * 16 + lc) * 32 + (quad ^ rsw) * 8];
            vf1[dj] = *(const bf16x8*)&VhB[(cur * 2 + 1) * 2048 + (dj * 16 + lc) * 32 + (quad ^ rsw) * 8];
        }

        for (int s = 0; s < 2; ++s) {
            // swapped QK^T: D[key][q] -> lane holds S[key=jn*16+quad*4+r][q=lc]
            f32x4 sa[4];
            __builtin_amdgcn_s_setprio(1);
            for (int jn = 0; jn < 4; ++jn) {
                f32x4 z = (f32x4){0.f, 0.f, 0.f, 0.f};
                z = __builtin_amdgcn_mfma_f32_16x16x32_bf16(kf0[jn], qf[s][0], z, 0, 0, 0);
                z = __builtin_amdgcn_mfma_f32_16x16x32_bf16(kf1[jn], qf[s][1], z, 0, 0, 0);
                sa[jn] = z;
            }
            __builtin_amdgcn_s_setprio(0);

            // softmax numerators: p = __expf(0.125*s + mb), mb in {0, -inf} (fast intrinsic)
            uint32 wd[4][2];
            float accs = 0.f;
            for (int jn = 0; jn < 4; ++jn) {
                float p0 = __expf(fmaf(sa[jn][0], 0.125f, mb[jn][0]));
                float p1 = __expf(fmaf(sa[jn][1], 0.125f, mb[jn][1]));
                float p2 = __expf(fmaf(sa[jn][2], 0.125f, mb[jn][2]));
                float p3 = __expf(fmaf(sa[jn][3], 0.125f, mb[jn][3]));
                accs += (p0 + p1) + (p2 + p3);
                __hip_bfloat16 h0 = __float2bfloat16(p0), h1 = __float2bfloat16(p1);
                __hip_bfloat16 h2 = __float2bfloat16(p2), h3 = __float2bfloat16(p3);
                wd[jn][0] = (uint32)*(unsigned short*)&h0 | ((uint32)*(unsigned short*)&h1 << 16);
                wd[jn][1] = (uint32)*(unsigned short*)&h2 | ((uint32)*(unsigned short*)&h3 << 16);
            }
            rsp2[s] += accs;

            // permlane-swap butterfly -> PV A-fragments (no selects; HW-verified v9)
            union { uint32 u[4]; bf16x8 v8; } pf0, pf1;
            for (int p = 0; p < 2; ++p) {
                uint32x2 a = __builtin_amdgcn_permlane32_swap(wd[0][p], wd[1][p], false, false);
                uint32x2 r = __builtin_amdgcn_permlane16_swap(a[0], a[1], false, false);
                pf0.u[p] = r[0]; pf0.u[2 + p] = r[1];
                uint32x2 a2 = __builtin_amdgcn_permlane32_swap(wd[2][p], wd[3][p], false, false);
                uint32x2 r2 = __builtin_amdgcn_permlane16_swap(a2[0], a2[1], false, false);
                pf1.u[p] = r2[0]; pf1.u[2 + p] = r2[1];
            }

            __builtin_amdgcn_s_setprio(1);
            for (int dj = 0; dj < 4; ++dj) {
                o[s][dj] = __builtin_amdgcn_mfma_f32_16x16x32_bf16(pf0.v8, vf0[dj], o[s][dj], 0, 0, 0);
                o[s][dj] = __builtin_amdgcn_mfma_f32_16x16x32_bf16(pf1.v8, vf1[dj], o[s][dj], 0, 0, 0);
            }
            __builtin_amdgcn_s_setprio(0);
        }
    }

    // ---- cross-group combine: group1 dumps unnormalized o + per-lane rsp to LDS ----
    __syncthreads();                       // all LDS reads + staged loads drained
    float* combo = (float*)smem;           // 128 rows x 66-stride f32 = 33.8 KB
    float* crs   = (float*)(smem + 33792); // 4 waves x 64 lanes x 2 = 512 f32
    if (g == 1) {
        for (int s = 0; s < 2; ++s) {
            crs[(wl * 64 + l) * 2 + s] = rsp2[s];
            for (int dj = 0; dj < 4; ++dj)
                for (int r = 0; r < 4; ++r)
                    combo[(s * 64 + wl * 16 + quad * 4 + r) * 66 + dj * 16 + lc] = o[s][dj][r];
        }
    }
    __syncthreads();
    if (g == 0) {
        for (int s = 0; s < 2; ++s) {
            float rs = rsp2[s] + crs[(wl * 64 + l) * 2 + s];
            rs += __shfl_xor(rs, 16);
            rs += __shfl_xor(rs, 32);
            for (int r = 0; r < 4; ++r) {
                float rq = __shfl(rs, (l & 48) | (quad * 4 + r));
                float linv = 1.0f / rq;
                int row = q0 + s * 64 + wl * 16 + quad * 4 + r;
                for (int dj = 0; dj < 4; ++dj) {
                    float ov = o[s][dj][r] + combo[(s * 64 + wl * 16 + quad * 4 + r) * 66 + dj * 16 + lc];
                    ctx[base + (size_t)row * DMODEL + dj * 16 + lc] = __float2bfloat16(ov * linv);
                }
            }
        }
    }
}

// ---------------- launcher ----------------
extern "C" void kernel_launch(void* const* d_in, const int* in_sizes, int n_in,
                              void* d_out, int out_size, void* d_ws, size_t ws_size,
                              hipStream_t stream) {
    const float* x    = (const float*)d_in[0];
    const int*   mask = (const int*)d_in[1];
    const float* wq = (const float*)d_in[2];
    const float* bq = (const float*)d_in[3];
    const float* wk = (const float*)d_in[4];
    const float* bk = (const float*)d_in[5];
    const float* wv = (const float*)d_in[6];
    const float* bv = (const float*)d_in[7];
    const float* wo = (const float*)d_in[8];
    const float* bo = (const float*)d_in[9];
    const float* ln1_a = (const float*)d_in[10];
    const float* ln1_b = (const float*)d_in[11];
    const float* ln2_a = (const float*)d_in[12];
    const float* ln2_b = (const float*)d_in[13];
    const float* w1 = (const float*)d_in[14];
    const float* b1 = (const float*)d_in[15];
    const float* w2 = (const float*)d_in[16];
    const float* b2 = (const float*)d_in[17];
    float* out = (float*)d_out;

    char* ws = (char*)d_ws;
    const size_t SZ_WT  = (size_t)DMODEL * DMODEL * 2;   // 2 MB bf16
    const size_t SZ_ACT = (size_t)NTOK * DMODEL * 2;     // 8 MB bf16
    const size_t SZ_WF  = (size_t)FDIM * DMODEL * 2;     // 8 MB bf16
    size_t off = 0;
    __hip_bfloat16* wqkvT = (__hip_bfloat16*)(ws + off); off += 3 * SZ_WT;  // [3072][1024]
    __hip_bfloat16* woT   = (__hip_bfloat16*)(ws + off); off += SZ_WT;
    __hip_bfloat16* w1T   = (__hip_bfloat16*)(ws + off); off += SZ_WF;     // [F][D]
    __hip_bfloat16* w2T   = (__hip_bfloat16*)(ws + off); off += SZ_WF;     // [D][F]
    __hip_bfloat16* h1    = (__hip_bfloat16*)(ws + off); off += SZ_ACT;
    __hip_bfloat16* qb    = (__hip_bfloat16*)(ws + off); off += SZ_ACT;
    __hip_bfloat16* kb    = (__hip_bfloat16*)(ws + off); off += SZ_ACT;
    __hip_bfloat16* vTb   = (__hip_bfloat16*)(ws + off); off += SZ_ACT;    // V^T per head
    __hip_bfloat16* ctx   = (__hip_bfloat16*)(ws + off); off += SZ_ACT;
    float*          x1    = (float*)(ws + off);          off += (size_t)NTOK * DMODEL * 4;
    __hip_bfloat16* h2    = (__hip_bfloat16*)(ws + off); off += SZ_ACT;
    __hip_bfloat16* ff1   = h1;  // reuse h1 region after attention

    dim3 tb(32, 8);
    transpose_cvt4_k<<<dim3(32, 32, 4), tb, 0, stream>>>(wq, wk, wv, wo, wqkvT, woT);
    transpose_cvt2_k<<<dim3(128, 32, 2), tb, 0, stream>>>(w1, w2, w1T, w2T);

    ln_kernel<<<NTOK, 256, 0, stream>>>(x, ln1_a, ln1_b, h1);

    gemm_qkv<<<dim3(3 * DMODEL / 128, NTOK / 128), 256, 0, stream>>>(h1, wqkvT, bq, bk, bv, qb, kb, vTb);

    attn_kernel<<<dim3(SEQ / 128, NB * NH), 512, 0, stream>>>(qb, kb, vTb, mask, ctx);

    gemm_bt_sk<2><<<dim3(DMODEL / 128, NTOK / 128), 512, 0, stream>>>(ctx, woT, bo, x, x1, NTOK, DMODEL, DMODEL);

    ln_kernel<<<NTOK, 256, 0, stream>>>(x1, ln2_a, ln2_b, h2);

    gemm_bt<1><<<dim3(FDIM / 128, NTOK / 128), 256, 0, stream>>>(h2, w1T, b1, nullptr, ff1, NTOK, FDIM, DMODEL);
    gemm_bt_sk<2><<<dim3(DMODEL / 128, NTOK / 128), 512, 0, stream>>>(ff1, w2T, b2, x1, out, NTOK, DMODEL, FDIM);
}

// Round 12
// 386.604 us; speedup vs baseline: 1.0321x; 1.0321x over previous
//
#include <hip/hip_runtime.h>
#include <hip/hip_bf16.h>
#include <math.h>

typedef __attribute__((ext_vector_type(8))) short bf16x8;   // 8 bf16 in 4 VGPRs
typedef __attribute__((ext_vector_type(4))) float f32x4;
typedef unsigned int uint32;
typedef __attribute__((ext_vector_type(2))) unsigned int uint32x2;

#define DMODEL 1024
#define SEQ    2048
#define NB     2
#define NH     16
#define HD     64
#define FDIM   4096
#define NTOK   (NB*SEQ)   // 4096

// ---------------- async global->LDS (wave-uniform LDS base + lane*16) ----------------
__device__ __forceinline__ void async16(const void* g, void* s) {
    __builtin_amdgcn_global_load_lds((const __attribute__((address_space(1))) unsigned int*)g,
                                     (__attribute__((address_space(3))) unsigned int*)s,
                                     16, 0, 0);
}

// ---------------- XCD-aware bijective block swizzle (T1, m204 form) ----------------
// Hardware dispatches linear block ids round-robin across the 8 XCDs; remap so each XCD
// processes a CONTIGUOUS run of row-major tiles -> same-A-panel blocks share one L2.
__device__ __forceinline__ int xcd_swizzle_lin(int lin, int nwg) {
    if (nwg & 7) return lin;          // bijective only when nwg % 8 == 0
    int q = nwg >> 3;
    return (lin & 7) * q + (lin >> 3);
}

// ---------------- merged 4x (1024x1024) transpose: z picks {wq,wk,wv,wo} ----------------
__global__ __launch_bounds__(256) void transpose_cvt4_k(const float* __restrict__ s0,
                                                        const float* __restrict__ s1,
                                                        const float* __restrict__ s2,
                                                        const float* __restrict__ s3,
                                                        __hip_bfloat16* __restrict__ d012,
                                                        __hip_bfloat16* __restrict__ d3) {
    __shared__ __hip_bfloat16 tile[32][33];
    const int z = blockIdx.z;
    const float* src = (z == 0) ? s0 : (z == 1) ? s1 : (z == 2) ? s2 : s3;
    __hip_bfloat16* dst = (z < 3) ? d012 + (size_t)z * DMODEL * DMODEL : d3;
    int tx = threadIdx.x, ty = threadIdx.y;
    int bx = blockIdx.x * 32, by = blockIdx.y * 32;
    for (int i = 0; i < 32; i += 8)
        tile[ty + i][tx] = __float2bfloat16(src[(size_t)(by + ty + i) * DMODEL + bx + tx]);
    __syncthreads();
    for (int i = 0; i < 32; i += 8)
        dst[(size_t)(bx + ty + i) * DMODEL + by + tx] = tile[tx][ty + i];
}

// ---------------- merged w1/w2 transpose: z=0: w1[1024][4096]->w1T[4096][1024];
// z=1: w2[4096][1024]->w2T[1024][4096]. Grid (128,32,2); z=1 swaps tile-index roles. ----
__global__ __launch_bounds__(256) void transpose_cvt2_k(const float* __restrict__ s0,
                                                        const float* __restrict__ s1,
                                                        __hip_bfloat16* __restrict__ d0,
                                                        __hip_bfloat16* __restrict__ d1) {
    __shared__ __hip_bfloat16 tile[32][33];
    const int z = blockIdx.z;
    const float* src = z ? s1 : s0;
    __hip_bfloat16* dst = z ? d1 : d0;
    const int R = z ? FDIM : DMODEL;     // src rows
    const int C = z ? DMODEL : FDIM;     // src cols
    const int bxi = z ? blockIdx.y : blockIdx.x;   // tile index over C
    const int byi = z ? blockIdx.x : blockIdx.y;   // tile index over R
    int tx = threadIdx.x, ty = threadIdx.y;
    int bx = bxi * 32, by = byi * 32;
    for (int i = 0; i < 32; i += 8)
        tile[ty + i][tx] = __float2bfloat16(src[(size_t)(by + ty + i) * C + bx + tx]);
    __syncthreads();
    for (int i = 0; i < 32; i += 8)
        dst[(size_t)(bx + ty + i) * R + by + tx] = tile[tx][ty + i];
}

// ---------------- layernorm: f32 row of 1024, unbiased std (ddof=1), /(std+eps) -> bf16 ----------------
__global__ __launch_bounds__(256) void ln_kernel(const float* __restrict__ x,
                                                 const float* __restrict__ alpha,
                                                 const float* __restrict__ beta,
                                                 __hip_bfloat16* __restrict__ out) {
    const int row = blockIdx.x, tid = threadIdx.x;
    const size_t base = (size_t)row * DMODEL;
    float v[4];
    for (int e = 0; e < 4; ++e) v[e] = x[base + tid * 4 + e];
    float s1 = v[0] + v[1] + v[2] + v[3];
    float s2 = v[0]*v[0] + v[1]*v[1] + v[2]*v[2] + v[3]*v[3];
    for (int off = 32; off > 0; off >>= 1) {
        s1 += __shfl_down(s1, off);
        s2 += __shfl_down(s2, off);
    }
    __shared__ float red[8];
    int w = tid >> 6, lane = tid & 63;
    if (lane == 0) { red[w * 2] = s1; red[w * 2 + 1] = s2; }
    __syncthreads();
    if (tid == 0) {
        float a = 0.f, b = 0.f;
        for (int i = 0; i < 4; ++i) { a += red[2 * i]; b += red[2 * i + 1]; }
        red[0] = a; red[1] = b;
    }
    __syncthreads();
    s1 = red[0]; s2 = red[1];
    float mean = s1 * (1.0f / DMODEL);
    float var  = fmaxf((s2 - (float)DMODEL * mean * mean) * (1.0f / (DMODEL - 1)), 0.f);
    float inv  = 1.0f / (sqrtf(var) + 1e-6f);
    for (int e = 0; e < 4; ++e) {
        int c = tid * 4 + e;
        float y = alpha[c] * (v[e] - mean) * inv + beta[c];
        out[base + c] = __float2bfloat16(y);
    }
}

// ---------------- GEMM (double-buffered, T2-swizzled, T1 XCD-swizzled): C = A @ Bt^T + bias ----------------
// EPI: 0 = bias -> bf16 ; 1 = bias+relu -> bf16 ; 2 = bias + f32 residual -> f32
template <int EPI>
__global__ __launch_bounds__(256) void gemm_bt(const __hip_bfloat16* __restrict__ A,
                                               const __hip_bfloat16* __restrict__ Bt,
                                               const float* __restrict__ bias,
                                               const float* __restrict__ res,
                                               void* __restrict__ Cout,
                                               int M, int N, int K) {
    __shared__ alignas(16) __hip_bfloat16 As[2][128 * 32];
    __shared__ alignas(16) __hip_bfloat16 Bs[2][128 * 32];
    const int tid = threadIdx.x, l = tid & 63;
    const int w = tid >> 6;
    const int wm = w >> 1, wn = w & 1, quad = l >> 4, lc = l & 15;
    const int lin = xcd_swizzle_lin(blockIdx.y * gridDim.x + blockIdx.x, gridDim.x * gridDim.y);
    const int row0 = (lin / gridDim.x) * 128, col0 = (lin % gridDim.x) * 128;
    const int lr = l >> 2, cb = l & 3;
    const int srow = 32 * w + lr;
    const int scol = (cb ^ ((lr >> 1) & 3)) * 8;     // pre-swizzled global source chunk
    const int rsw  = (lc >> 1) & 3;                  // read-side un-swizzle

    f32x4 acc[4][4];
    for (int i = 0; i < 4; ++i)
        for (int j = 0; j < 4; ++j) acc[i][j] = (f32x4){0.f, 0.f, 0.f, 0.f};

    // prologue: stage tile 0 into buffer 0
    for (int c = 0; c < 2; ++c) {
        async16(A  + (size_t)(row0 + srow + 16 * c) * K + scol, (char*)&As[0][0] + w * 2048 + c * 1024);
        async16(Bt + (size_t)(col0 + srow + 16 * c) * K + scol, (char*)&Bs[0][0] + w * 2048 + c * 1024);
    }
    const int NKT = K / 32;
    for (int kt = 0; kt < NKT; ++kt) {
        const int cur = kt & 1;
        __syncthreads();   // drains stage(kt); also fences prev-iter LDS reads
        if (kt + 1 < NKT) {
            const int k1 = (kt + 1) * 32;
            for (int c = 0; c < 2; ++c) {
                async16(A  + (size_t)(row0 + srow + 16 * c) * K + k1 + scol, (char*)&As[cur ^ 1][0] + w * 2048 + c * 1024);
                async16(Bt + (size_t)(col0 + srow + 16 * c) * K + k1 + scol, (char*)&Bs[cur ^ 1][0] + w * 2048 + c * 1024);
            }
        }
        bf16x8 af[4], bfr[4];
        for (int i = 0; i < 4; ++i) af[i]  = *(const bf16x8*)&As[cur][(64 * wm + 16 * i + lc) * 32 + (quad ^ rsw) * 8];
        for (int j = 0; j < 4; ++j) bfr[j] = *(const bf16x8*)&Bs[cur][(64 * wn + 16 * j + lc) * 32 + (quad ^ rsw) * 8];
        for (int i = 0; i < 4; ++i)
            for (int j = 0; j < 4; ++j)
                acc[i][j] = __builtin_amdgcn_mfma_f32_16x16x32_bf16(af[i], bfr[j], acc[i][j], 0, 0, 0);
    }

    __hip_bfloat16* Cb = (__hip_bfloat16*)Cout;
    float* Cf = (float*)Cout;
    for (int j = 0; j < 4; ++j) {
        int col = col0 + 64 * wn + 16 * j + lc;
        float bv = bias[col];
        for (int i = 0; i < 4; ++i) {
            int rbase = row0 + 64 * wm + 16 * i + quad * 4;
            for (int r = 0; r < 4; ++r) {
                size_t idx = (size_t)(rbase + r) * N + col;
                float vacc = acc[i][j][r] + bv;
                if (EPI == 0)      Cb[idx] = __float2bfloat16(vacc);
                else if (EPI == 1) Cb[idx] = __float2bfloat16(fmaxf(vacc, 0.f));
                else               Cf[idx] = vacc + res[idx];
            }
        }
    }
}

// ---------------- in-block split-K GEMM for small-N shapes (N=1024 -> 256 blocks = 1/CU) ----------------
template <int EPI>
__global__ __launch_bounds__(512) void gemm_bt_sk(const __hip_bfloat16* __restrict__ A,
                                                  const __hip_bfloat16* __restrict__ Bt,
                                                  const float* __restrict__ bias,
                                                  const float* __restrict__ res,
                                                  void* __restrict__ Cout,
                                                  int M, int N, int K) {
    __shared__ alignas(16) char smem[65536];   // [As: 2g x 2buf x 8KB][Bs: same]
    const int tid = threadIdx.x, l = tid & 63;
    const int w = tid >> 6;           // 0..7
    const int g = w >> 2;             // K-group
    const int wl = w & 3;             // wave within group
    const int wm = wl >> 1, wn = wl & 1, quad = l >> 4, lc = l & 15;
    const int lin = xcd_swizzle_lin(blockIdx.y * gridDim.x + blockIdx.x, gridDim.x * gridDim.y);
    const int row0 = (lin / gridDim.x) * 128, col0 = (lin % gridDim.x) * 128;
    const int lr = l >> 2, cb = l & 3;
    const int srow = 32 * wl + lr;
    const int scol = (cb ^ ((lr >> 1) & 3)) * 8;
    const int rsw  = (lc >> 1) & 3;
    const int Kh = K >> 1;
    const int kbase = g * Kh;

    char* AsBase = smem + (size_t)g * 16384;
    char* BsBase = smem + 32768 + (size_t)g * 16384;

    f32x4 acc[4][4];
    for (int i = 0; i < 4; ++i)
        for (int j = 0; j < 4; ++j) acc[i][j] = (f32x4){0.f, 0.f, 0.f, 0.f};

    // prologue: stage tile 0 into buffer 0 (per group)
    for (int c = 0; c < 2; ++c) {
        async16(A  + (size_t)(row0 + srow + 16 * c) * K + kbase + scol, AsBase + wl * 2048 + c * 1024);
        async16(Bt + (size_t)(col0 + srow + 16 * c) * K + kbase + scol, BsBase + wl * 2048 + c * 1024);
    }
    const int NKT = Kh / 32;
    for (int kt = 0; kt < NKT; ++kt) {
        const int cur = kt & 1;
        __syncthreads();
        if (kt + 1 < NKT) {
            const int k1 = kbase + (kt + 1) * 32;
            for (int c = 0; c < 2; ++c) {
                async16(A  + (size_t)(row0 + srow + 16 * c) * K + k1 + scol, AsBase + (cur ^ 1) * 8192 + wl * 2048 + c * 1024);
                async16(Bt + (size_t)(col0 + srow + 16 * c) * K + k1 + scol, BsBase + (cur ^ 1) * 8192 + wl * 2048 + c * 1024);
            }
        }
        const __hip_bfloat16* Asc = (const __hip_bfloat16*)(AsBase + cur * 8192);
        const __hip_bfloat16* Bsc = (const __hip_bfloat16*)(BsBase + cur * 8192);
        bf16x8 af[4], bfr[4];
        for (int i = 0; i < 4; ++i) af[i]  = *(const bf16x8*)&Asc[(64 * wm + 16 * i + lc) * 32 + (quad ^ rsw) * 8];
        for (int j = 0; j < 4; ++j) bfr[j] = *(const bf16x8*)&Bsc[(64 * wn + 16 * j + lc) * 32 + (quad ^ rsw) * 8];
        for (int i = 0; i < 4; ++i)
            for (int j = 0; j < 4; ++j)
                acc[i][j] = __builtin_amdgcn_mfma_f32_16x16x32_bf16(af[i], bfr[j], acc[i][j], 0, 0, 0);
    }

    // combine: repurpose the whole 64 KB as a 128x128 f32 tile
    __syncthreads();                       // all LDS reads + staged loads drained
    float* comb = (float*)smem;
    if (g == 1) {
        for (int j = 0; j < 4; ++j) {
            int col = 64 * wn + 16 * j + lc;
            int ccol = col ^ ((quad & 1) << 4);          // 2-way-max bank spread
            for (int i = 0; i < 4; ++i) {
                int rb = 64 * wm + 16 * i + quad * 4;
                for (int r = 0; r < 4; ++r)
                    comb[(rb + r) * 128 + ccol] = acc[i][j][r];
            }
        }
    }
    __syncthreads();
    if (g == 0) {
        __hip_bfloat16* Cb = (__hip_bfloat16*)Cout;
        float* Cf = (float*)Cout;
        for (int j = 0; j < 4; ++j) {
            int coll = 64 * wn + 16 * j + lc;
            int ccol = coll ^ ((quad & 1) << 4);
            int col  = col0 + coll;
            float bv = bias[col];
            for (int i = 0; i < 4; ++i) {
                int rbl = 64 * wm + 16 * i + quad * 4;
                for (int r = 0; r < 4; ++r) {
                    size_t idx = (size_t)(row0 + rbl + r) * N + col;
                    float vacc = acc[i][j][r] + comb[(rbl + r) * 128 + ccol] + bv;
                    if (EPI == 0)      Cb[idx] = __float2bfloat16(vacc);
                    else if (EPI == 1) Cb[idx] = __float2bfloat16(fmaxf(vacc, 0.f));
                    else               Cf[idx] = vacc + res[idx];
                }
            }
        }
    }
}

// ---------------- fused QKV GEMM (double-buffered, T2 + T1 swizzled): N = 3072 = [q | k | v] ----------------
__global__ __launch_bounds__(256) void gemm_qkv(const __hip_bfloat16* __restrict__ A,
                                                const __hip_bfloat16* __restrict__ Bt,
                                                const float* __restrict__ bq,
                                                const float* __restrict__ bk,
                                                const float* __restrict__ bv,
                                                __hip_bfloat16* __restrict__ qout,
                                                __hip_bfloat16* __restrict__ kout,
                                                __hip_bfloat16* __restrict__ vTout) {
    const int K = DMODEL;
    __shared__ alignas(16) __hip_bfloat16 As[2][128 * 32];
    __shared__ alignas(16) __hip_bfloat16 Bs[2][128 * 32];
    const int tid = threadIdx.x, l = tid & 63;
    const int w = tid >> 6;
    const int wm = w >> 1, wn = w & 1, quad = l >> 4, lc = l & 15;
    const int lin = xcd_swizzle_lin(blockIdx.y * gridDim.x + blockIdx.x, gridDim.x * gridDim.y);
    const int row0 = (lin / gridDim.x) * 128, col0 = (lin % gridDim.x) * 128;
    const int lr = l >> 2, cb = l & 3;
    const int srow = 32 * w + lr;
    const int scol = (cb ^ ((lr >> 1) & 3)) * 8;
    const int rsw  = (lc >> 1) & 3;

    f32x4 acc[4][4];
    for (int i = 0; i < 4; ++i)
        for (int j = 0; j < 4; ++j) acc[i][j] = (f32x4){0.f, 0.f, 0.f, 0.f};

    for (int c = 0; c < 2; ++c) {
        async16(A  + (size_t)(row0 + srow + 16 * c) * K + scol, (char*)&As[0][0] + w * 2048 + c * 1024);
        async16(Bt + (size_t)(col0 + srow + 16 * c) * K + scol, (char*)&Bs[0][0] + w * 2048 + c * 1024);
    }
    const int NKT = K / 32;
    for (int kt = 0; kt < NKT; ++kt) {
        const int cur = kt & 1;
        __syncthreads();
        if (kt + 1 < NKT) {
            const int k1 = (kt + 1) * 32;
            for (int c = 0; c < 2; ++c) {
                async16(A  + (size_t)(row0 + srow + 16 * c) * K + k1 + scol, (char*)&As[cur ^ 1][0] + w * 2048 + c * 1024);
                async16(Bt + (size_t)(col0 + srow + 16 * c) * K + k1 + scol, (char*)&Bs[cur ^ 1][0] + w * 2048 + c * 1024);
            }
        }
        bf16x8 af[4], bfr[4];
        for (int i = 0; i < 4; ++i) af[i]  = *(const bf16x8*)&As[cur][(64 * wm + 16 * i + lc) * 32 + (quad ^ rsw) * 8];
        for (int j = 0; j < 4; ++j) bfr[j] = *(const bf16x8*)&Bs[cur][(64 * wn + 16 * j + lc) * 32 + (quad ^ rsw) * 8];
        for (int i = 0; i < 4; ++i)
            for (int j = 0; j < 4; ++j)
                acc[i][j] = __builtin_amdgcn_mfma_f32_16x16x32_bf16(af[i], bfr[j], acc[i][j], 0, 0, 0);
    }

    const int seg = col0 >> 10;                       // block-uniform: 0=q, 1=k, 2=v
    const float* bias = (seg == 0) ? bq : (seg == 1) ? bk : bv;
    for (int j = 0; j < 4; ++j) {
        int col  = col0 + 64 * wn + 16 * j + lc;
        int colm = col & (DMODEL - 1);
        float bvx = bias[colm];
        for (int i = 0; i < 4; ++i) {
            int rbase = row0 + 64 * wm + 16 * i + quad * 4;
            for (int r = 0; r < 4; ++r) {
                int trow = rbase + r;
                float vacc = acc[i][j][r] + bvx;
                if (seg == 2) {
                    // V^T: token t=(b,s), colm=(h,d) -> [(b*NH+h)*HD+d][s]
                    int bb = trow >> 11, s = trow & (SEQ - 1);
                    int hh = colm >> 6, d = colm & (HD - 1);
                    vTout[((size_t)(bb * NH + hh) * HD + d) * SEQ + s] = __float2bfloat16(vacc);
                } else {
                    __hip_bfloat16* dst = (seg == 0) ? qout : kout;
                    dst[(size_t)trow * DMODEL + colm] = __float2bfloat16(vacc);
                }
            }
        }
    }
}

// ---------------- flash attention v14 (FINAL, unchanged): QBLK=128 + in-block KV-split ----------------
// Measured-best (78.6-79.4us band; 89.8us in R11 = session clock noise on identical code).
// Variant sweep complete: QBLK=64 100us, QBLK=256 103us (VGPR cliff), exp2f 90us (libm),
// head-major 90us, no-LDS 138us (TA-bound scattered gathers).
__global__ __launch_bounds__(512) void attn_kernel(const __hip_bfloat16* __restrict__ q,
                                                   const __hip_bfloat16* __restrict__ k,
                                                   const __hip_bfloat16* __restrict__ vT,
                                                   const int* __restrict__ mask,
                                                   __hip_bfloat16* __restrict__ ctx) {
    const int qt = blockIdx.x, bh = blockIdx.y;
    const int b = bh >> 4;
    const int q0 = qt * 128;
    const int tid = threadIdx.x, w = tid >> 6, l = tid & 63, quad = l >> 4, lc = l & 15;
    const int g = w >> 2, wl = w & 3;

    __shared__ alignas(16) char smem[65536];
    __hip_bfloat16* KhB = (__hip_bfloat16*)(smem + (size_t)g * 32768);
    __hip_bfloat16* VhB = (__hip_bfloat16*)(smem + (size_t)g * 32768 + 16384);

    const size_t base   = (size_t)b * SEQ * DMODEL + (size_t)(bh & 15) * HD;
    const size_t vtbase = (size_t)bh * HD * SEQ;
    const int gk = g * (SEQ / 2);     // group key base

    bf16x8 qf[2][2];
    for (int s = 0; s < 2; ++s) {
        const __hip_bfloat16* qrow = &q[base + (size_t)(q0 + s * 64 + wl * 16 + lc) * DMODEL];
        qf[s][0] = *(const bf16x8*)&qrow[quad * 8];
        qf[s][1] = *(const bf16x8*)&qrow[32 + quad * 8];
    }

    f32x4 o[2][4];
    for (int s = 0; s < 2; ++s)
        for (int dj = 0; dj < 4; ++dj) o[s][dj] = (f32x4){0.f, 0.f, 0.f, 0.f};
    float rsp2[2] = {0.f, 0.f};

    const int lr  = l >> 2, cb = l & 3;
    const int cbsw = ((cb ^ ((lr >> 1) & 3))) * 8;   // pre-swizzled global source block (stage side)
    const int rsw  = (lc >> 1) & 3;                  // read-side XOR

    // prologue: stage tile 0 into buffer 0 (global source pre-swizzled; LDS dest linear)
    for (int c = 0; c < 2; ++c) {
        const int W = wl * 2 + c;
        const int rr = (W & 3) * 16 + lr, cc8 = (W >> 2) * 32 + cbsw;
        async16(&k [base   + (size_t)(gk + rr) * DMODEL + cc8], (char*)KhB + W * 1024);
        async16(&vT[vtbase + (size_t)rr * SEQ + gk + cc8],      (char*)VhB + W * 1024);
    }

    const int NT = SEQ / 128;   // 16 tiles of 64 keys per group
    for (int kt = 0; kt < NT; ++kt) {
        const int k0 = gk + kt * 64;
        const int cur = kt & 1;

        __syncthreads();   // drains stage(kt); fences prev-iter fragment reads
        if (kt + 1 < NT) {
            const int k1 = k0 + 64;
            for (int c = 0; c < 2; ++c) {
                const int W = wl * 2 + c;
                const int rr = (W & 3) * 16 + lr, cc8 = (W >> 2) * 32 + cbsw;
                async16(&k [base   + (size_t)(k1 + rr) * DMODEL + cc8], (char*)KhB + (cur ^ 1) * 8192 + W * 1024);
                async16(&vT[vtbase + (size_t)rr * SEQ + k1 + cc8],      (char*)VhB + (cur ^ 1) * 8192 + W * 1024);
            }
        }
        // mask -> additive bias (0 / -inf), once per tile (16B-aligned int4 loads)
        float mb[4][4];
        for (int jn = 0; jn < 4; ++jn) {
            int4 mi = *(const int4*)&mask[b * SEQ + k0 + jn * 16 + quad * 4];
            mb[jn][0] = mi.x ? 0.f : -INFINITY;
            mb[jn][1] = mi.y ? 0.f : -INFINITY;
            mb[jn][2] = mi.z ? 0.f : -INFINITY;
            mb[jn][3] = mi.w ? 0.f : -INFINITY;
        }

        bf16x8 kf0[4], kf1[4];
        for (int jn = 0; jn < 4; ++jn) {
            kf0[jn] = *(const bf16x8*)&KhB[(cur * 2 + 0) * 2048 + (jn * 16 + lc) * 32 + (quad ^ rsw) * 8];
            kf1[jn] = *(const bf16x8*)&KhB[(cur * 2 + 1) * 2048 + (jn * 16 + lc) * 32 + (quad ^ rsw) * 8];
        }
        bf16x8 vf0[4], vf1[4];
        for (int dj = 0; dj < 4; ++dj) {
            vf0[dj] = *(const bf16x8*)&VhB[(cur * 2 + 0) * 2048 + (dj * 16 + lc) * 32 + (quad ^ rsw) * 8];
            vf1[dj] = *(const bf16x8*)&VhB[(cur * 2 + 1) * 2048 + (dj * 16 + lc) * 32 + (quad ^ rsw) * 8];
        }

        for (int s = 0; s < 2; ++s) {
            // swapped QK^T: D[key][q] -> lane holds S[key=jn*16+quad*4+r][q=lc]
            f32x4 sa[4];
            __builtin_amdgcn_s_setprio(1);
            for (int jn = 0; jn < 4; ++jn) {
                f32x4 z = (f32x4){0.f, 0.f, 0.f, 0.f};
                z = __builtin_amdgcn_mfma_f32_16x16x32_bf16(kf0[jn], qf[s][0], z, 0, 0, 0);
                z = __builtin_amdgcn_mfma_f32_16x16x32_bf16(kf1[jn], qf[s][1], z, 0, 0, 0);
                sa[jn] = z;
            }
            __builtin_amdgcn_s_setprio(0);

            // softmax numerators: p = __expf(0.125*s + mb), mb in {0, -inf} (fast intrinsic)
            uint32 wd[4][2];
            float accs = 0.f;
            for (int jn = 0; jn < 4; ++jn) {
                float p0 = __expf(fmaf(sa[jn][0], 0.125f, mb[jn][0]));
                float p1 = __expf(fmaf(sa[jn][1], 0.125f, mb[jn][1]));
                float p2 = __expf(fmaf(sa[jn][2], 0.125f, mb[jn][2]));
                float p3 = __expf(fmaf(sa[jn][3], 0.125f, mb[jn][3]));
                accs += (p0 + p1) + (p2 + p3);
                __hip_bfloat16 h0 = __float2bfloat16(p0), h1 = __float2bfloat16(p1);
                __hip_bfloat16 h2 = __float2bfloat16(p2), h3 = __float2bfloat16(p3);
                wd[jn][0] = (uint32)*(unsigned short*)&h0 | ((uint32)*(unsigned short*)&h1 << 16);
                wd[jn][1] = (uint32)*(unsigned short*)&h2 | ((uint32)*(unsigned short*)&h3 << 16);
            }
            rsp2[s] += accs;

            // permlane-swap butterfly -> PV A-fragments (no selects; HW-verified v9)
            union { uint32 u[4]; bf16x8 v8; } pf0, pf1;
            for (int p = 0; p < 2; ++p) {
                uint32x2 a = __builtin_amdgcn_permlane32_swap(wd[0][p], wd[1][p], false, false);
                uint32x2 r = __builtin_amdgcn_permlane16_swap(a[0], a[1], false, false);
                pf0.u[p] = r[0]; pf0.u[2 + p] = r[1];
                uint32x2 a2 = __builtin_amdgcn_permlane32_swap(wd[2][p], wd[3][p], false, false);
                uint32x2 r2 = __builtin_amdgcn_permlane16_swap(a2[0], a2[1], false, false);
                pf1.u[p] = r2[0]; pf1.u[2 + p] = r2[1];
            }

            __builtin_amdgcn_s_setprio(1);
            for (int dj = 0; dj < 4; ++dj) {
                o[s][dj] = __builtin_amdgcn_mfma_f32_16x16x32_bf16(pf0.v8, vf0[dj], o[s][dj], 0, 0, 0);
                o[s][dj] = __builtin_amdgcn_mfma_f32_16x16x32_bf16(pf1.v8, vf1[dj], o[s][dj], 0, 0, 0);
            }
            __builtin_amdgcn_s_setprio(0);
        }
    }

    // ---- cross-group combine: group1 dumps unnormalized o + per-lane rsp to LDS ----
    __syncthreads();                       // all LDS reads + staged loads drained
    float* combo = (float*)smem;           // 128 rows x 66-stride f32 = 33.8 KB
    float* crs   = (float*)(smem + 33792); // 4 waves x 64 lanes x 2 = 512 f32
    if (g == 1) {
        for (int s = 0; s < 2; ++s) {
            crs[(wl * 64 + l) * 2 + s] = rsp2[s];
            for (int dj = 0; dj < 4; ++dj)
                for (int r = 0; r < 4; ++r)
                    combo[(s * 64 + wl * 16 + quad * 4 + r) * 66 + dj * 16 + lc] = o[s][dj][r];
        }
    }
    __syncthreads();
    if (g == 0) {
        for (int s = 0; s < 2; ++s) {
            float rs = rsp2[s] + crs[(wl * 64 + l) * 2 + s];
            rs += __shfl_xor(rs, 16);
            rs += __shfl_xor(rs, 32);
            for (int r = 0; r < 4; ++r) {
                float rq = __shfl(rs, (l & 48) | (quad * 4 + r));
                float linv = 1.0f / rq;
                int row = q0 + s * 64 + wl * 16 + quad * 4 + r;
                for (int dj = 0; dj < 4; ++dj) {
                    float ov = o[s][dj][r] + combo[(s * 64 + wl * 16 + quad * 4 + r) * 66 + dj * 16 + lc];
                    ctx[base + (size_t)row * DMODEL + dj * 16 + lc] = __float2bfloat16(ov * linv);
                }
            }
        }
    }
}

// ---------------- launcher ----------------
extern "C" void kernel_launch(void* const* d_in, const int* in_sizes, int n_in,
                              void* d_out, int out_size, void* d_ws, size_t ws_size,
                              hipStream_t stream) {
    const float* x    = (const float*)d_in[0];
    const int*   mask = (const int*)d_in[1];
    const float* wq = (const float*)d_in[2];
    const float* bq = (const float*)d_in[3];
    const float* wk = (const float*)d_in[4];
    const float* bk = (const float*)d_in[5];
    const float* wv = (const float*)d_in[6];
    const float* bv = (const float*)d_in[7];
    const float* wo = (const float*)d_in[8];
    const float* bo = (const float*)d_in[9];
    const float* ln1_a = (const float*)d_in[10];
    const float* ln1_b = (const float*)d_in[11];
    const float* ln2_a = (const float*)d_in[12];
    const float* ln2_b = (const float*)d_in[13];
    const float* w1 = (const float*)d_in[14];
    const float* b1 = (const float*)d_in[15];
    const float* w2 = (const float*)d_in[16];
    const float* b2 = (const float*)d_in[17];
    float* out = (float*)d_out;

    char* ws = (char*)d_ws;
    const size_t SZ_WT  = (size_t)DMODEL * DMODEL * 2;   // 2 MB bf16
    const size_t SZ_ACT = (size_t)NTOK * DMODEL * 2;     // 8 MB bf16
    const size_t SZ_WF  = (size_t)FDIM * DMODEL * 2;     // 8 MB bf16
    size_t off = 0;
    __hip_bfloat16* wqkvT = (__hip_bfloat16*)(ws + off); off += 3 * SZ_WT;  // [3072][1024]
    __hip_bfloat16* woT   = (__hip_bfloat16*)(ws + off); off += SZ_WT;
    __hip_bfloat16* w1T   = (__hip_bfloat16*)(ws + off); off += SZ_WF;     // [F][D]
    __hip_bfloat16* w2T   = (__hip_bfloat16*)(ws + off); off += SZ_WF;     // [D][F]
    __hip_bfloat16* h1    = (__hip_bfloat16*)(ws + off); off += SZ_ACT;
    __hip_bfloat16* qb    = (__hip_bfloat16*)(ws + off); off += SZ_ACT;
    __hip_bfloat16* kb    = (__hip_bfloat16*)(ws + off); off += SZ_ACT;
    __hip_bfloat16* vTb   = (__hip_bfloat16*)(ws + off); off += SZ_ACT;    // V^T per head
    __hip_bfloat16* ctx   = (__hip_bfloat16*)(ws + off); off += SZ_ACT;
    float*          x1    = (float*)(ws + off);          off += (size_t)NTOK * DMODEL * 4;
    __hip_bfloat16* h2    = (__hip_bfloat16*)(ws + off); off += SZ_ACT;
    __hip_bfloat16* ff1   = h1;  // reuse h1 region after attention

    dim3 tb(32, 8);
    transpose_cvt4_k<<<dim3(32, 32, 4), tb, 0, stream>>>(wq, wk, wv, wo, wqkvT, woT);
    transpose_cvt2_k<<<dim3(128, 32, 2), tb, 0, stream>>>(w1, w2, w1T, w2T);

    ln_kernel<<<NTOK, 256, 0, stream>>>(x, ln1_a, ln1_b, h1);

    gemm_qkv<<<dim3(3 * DMODEL / 128, NTOK / 128), 256, 0, stream>>>(h1, wqkvT, bq, bk, bv, qb, kb, vTb);

    attn_kernel<<<dim3(SEQ / 128, NB * NH), 512, 0, stream>>>(qb, kb, vTb, mask, ctx);

    gemm_bt_sk<2><<<dim3(DMODEL / 128, NTOK / 128), 512, 0, stream>>>(ctx, woT, bo, x, x1, NTOK, DMODEL, DMODEL);

    ln_kernel<<<NTOK, 256, 0, stream>>>(x1, ln2_a, ln2_b, h2);

    gemm_bt<1><<<dim3(FDIM / 128, NTOK / 128), 256, 0, stream>>>(h2, w1T, b1, nullptr, ff1, NTOK, FDIM, DMODEL);
    gemm_bt_sk<2><<<dim3(DMODEL / 128, NTOK / 128), 512, 0, stream>>>(ff1, w2T, b2, x1, out, NTOK, DMODEL, FDIM);
}